// Round 1
// baseline (373.756 us; speedup 1.0000x reference)
//
#include <hip/hip_runtime.h>
#include <math.h>

// Problem constants (match reference): B=4096, T=200, D=64
#define TT 200
#define DD 64
#define KPAD 65   // +1 pad: bank = (t*65+d)%32 = (t+d)%32 -> conflict-free both ways

__device__ __forceinline__ float sigmoidf_(float x) {
    return 1.0f / (1.0f + __expf(-x));
}

__global__ __launch_bounds__(256) void din_attn_kernel(
    const float* __restrict__ queries,     // [B,64]
    const float* __restrict__ keys,        // [B,200,64]
    const int*   __restrict__ keys_length, // [B]
    const float* __restrict__ W1,          // [256,16]
    const float* __restrict__ b1,          // [16]
    const float* __restrict__ W2,          // [16,8]
    const float* __restrict__ b2,          // [8]
    const float* __restrict__ W3,          // [8,1]
    const float* __restrict__ b3,          // [1]
    const float* __restrict__ W4,          // [64,64]
    const float* __restrict__ b4,          // [64]
    float* __restrict__ out)               // [B,64]
{
    __shared__ float Ks[TT * KPAD];     // 52000 B, padded keys tile
    __shared__ float Ms[DD * 16];       // folded first-layer weight, per batch
    __shared__ float cpart[DD * 16];    // scratch for c reduction
    __shared__ float qs[DD];
    __shared__ float cvec[16];
    __shared__ float w2s[16 * 8];
    __shared__ float w3s[8];
    __shared__ float b2s[8];
    __shared__ float b3sh[1];
    __shared__ float scoresS[256];      // raw scores -> attn weights
    __shared__ float red[4 * 64];       // cross-wave reduction buffer
    __shared__ float tmpv[64];          // attn-weighted key sum

    const int tid = threadIdx.x;
    const int b   = blockIdx.x;
    const int len = keys_length[b];

    // ---- stage small operands ----
    if (tid < 64)        qs[tid]        = queries[b * DD + tid];
    else if (tid < 192)  w2s[tid - 64]  = W2[tid - 64];
    else if (tid < 200)  w3s[tid - 192] = W3[tid - 192];
    else if (tid < 208)  b2s[tid - 200] = b2[tid - 200];
    else if (tid == 208) b3sh[0]        = b3[0];

    // ---- stage keys[b] -> padded LDS (coalesced float4 global reads) ----
    {
        const float4* kg = (const float4*)(keys + (size_t)b * (TT * DD));
        for (int i = tid; i < (TT * DD) / 4; i += 256) {
            float4 v = kg[i];
            int t  = i >> 4;          // 16 float4 per row of 64
            int d0 = (i & 15) << 2;
            float* p = &Ks[t * KPAD + d0];
            p[0] = v.x; p[1] = v.y; p[2] = v.z; p[3] = v.w;
        }
    }
    __syncthreads();

    // ---- fold W1: M[d][h] = W1b - W1c + q[d]*W1d ; cpart[d][h] = q[d]*(W1a + W1c) ----
    {
        const float4* W1v = (const float4*)W1;   // [256][4] of float4
        const int d  = tid >> 2;
        const int hg = tid & 3;
        const float q = qs[d];
        float4 a  = W1v[(0   + d) * 4 + hg];
        float4 bb = W1v[(64  + d) * 4 + hg];
        float4 cc = W1v[(128 + d) * 4 + hg];
        float4 dd = W1v[(192 + d) * 4 + hg];
        const int base = d * 16 + hg * 4;
        cpart[base + 0] = q * (a.x + cc.x);
        cpart[base + 1] = q * (a.y + cc.y);
        cpart[base + 2] = q * (a.z + cc.z);
        cpart[base + 3] = q * (a.w + cc.w);
        Ms[base + 0] = bb.x - cc.x + q * dd.x;
        Ms[base + 1] = bb.y - cc.y + q * dd.y;
        Ms[base + 2] = bb.z - cc.z + q * dd.z;
        Ms[base + 3] = bb.w - cc.w + q * dd.w;
    }
    __syncthreads();
    if (tid < 16) {
        float s = b1[tid];
        for (int d = 0; d < DD; d++) s += cpart[d * 16 + tid];
        cvec[tid] = s;
    }
    __syncthreads();

    // ---- scorer: thread t computes score(b,t) ----
    float sc = -INFINITY;
    if (tid < TT) {
        float acc[16];
        #pragma unroll
        for (int h = 0; h < 16; h++) acc[h] = cvec[h];
        const float* krow = &Ks[tid * KPAD];
        #pragma unroll 4
        for (int d = 0; d < DD; d++) {
            float kv = krow[d];                        // conflict-free (pad)
            const float4* mrow = (const float4*)&Ms[d * 16];  // wave-uniform broadcast
            float4 m0 = mrow[0], m1 = mrow[1], m2 = mrow[2], m3 = mrow[3];
            acc[0]  = fmaf(kv, m0.x, acc[0]);
            acc[1]  = fmaf(kv, m0.y, acc[1]);
            acc[2]  = fmaf(kv, m0.z, acc[2]);
            acc[3]  = fmaf(kv, m0.w, acc[3]);
            acc[4]  = fmaf(kv, m1.x, acc[4]);
            acc[5]  = fmaf(kv, m1.y, acc[5]);
            acc[6]  = fmaf(kv, m1.z, acc[6]);
            acc[7]  = fmaf(kv, m1.w, acc[7]);
            acc[8]  = fmaf(kv, m2.x, acc[8]);
            acc[9]  = fmaf(kv, m2.y, acc[9]);
            acc[10] = fmaf(kv, m2.z, acc[10]);
            acc[11] = fmaf(kv, m2.w, acc[11]);
            acc[12] = fmaf(kv, m3.x, acc[12]);
            acc[13] = fmaf(kv, m3.y, acc[13]);
            acc[14] = fmaf(kv, m3.z, acc[14]);
            acc[15] = fmaf(kv, m3.w, acc[15]);
        }
        float h1v[16];
        #pragma unroll
        for (int h = 0; h < 16; h++) h1v[h] = sigmoidf_(acc[h]);
        float h2v[8];
        #pragma unroll
        for (int k = 0; k < 8; k++) {
            float s2 = b2s[k];
            #pragma unroll
            for (int h = 0; h < 16; h++) s2 = fmaf(h1v[h], w2s[h * 8 + k], s2);
            h2v[k] = sigmoidf_(s2);
        }
        float s3 = b3sh[0];
        #pragma unroll
        for (int k = 0; k < 8; k++) s3 = fmaf(h2v[k], w3s[k], s3);
        if (tid >= len) s3 = -4294967295.0f;   // NEG_INF (rounds to -2^32 like the f32 ref)
        sc = s3 * 0.125f;                      // / sqrt(64)
    }

    // ---- softmax over T (block reduce: wave shuffle + LDS) ----
    float m = sc;
    #pragma unroll
    for (int off = 32; off >= 1; off >>= 1) m = fmaxf(m, __shfl_xor(m, off, 64));
    if ((tid & 63) == 0) red[tid >> 6] = m;
    __syncthreads();
    m = fmaxf(fmaxf(red[0], red[1]), fmaxf(red[2], red[3]));

    float p = (tid < TT) ? __expf(sc - m) : 0.0f;
    float ssum = p;
    #pragma unroll
    for (int off = 32; off >= 1; off >>= 1) ssum += __shfl_xor(ssum, off, 64);
    __syncthreads();                    // done reading red (max partials)
    if ((tid & 63) == 0) red[tid >> 6] = ssum;
    __syncthreads();
    const float inv = 1.0f / (red[0] + red[1] + red[2] + red[3]);
    if (tid < TT) scoresS[tid] = p * inv;
    __syncthreads();

    // ---- weighted key sum: wave w covers 50 t's, lane = d ----
    const int w    = tid >> 6;
    const int lane = tid & 63;
    float ws = 0.0f;
    for (int t = w * 50; t < w * 50 + 50; t++)
        ws = fmaf(scoresS[t], Ks[t * KPAD + lane], ws);   // broadcast + conflict-free
    red[w * 64 + lane] = ws;
    __syncthreads();
    if (tid < 64) tmpv[tid] = red[tid] + red[64 + tid] + red[128 + tid] + red[192 + tid];
    __syncthreads();

    // ---- out = tmpv @ W4 + b4 ; wave w covers i in [16w,16w+16) ----
    float po = 0.0f;
    {
        const float* w4p = W4 + (size_t)(w * 16) * 64 + lane;
        #pragma unroll
        for (int i = 0; i < 16; i++)
            po = fmaf(tmpv[w * 16 + i], w4p[i * 64], po);  // coalesced global, L2-hot
    }
    red[w * 64 + lane] = po;
    __syncthreads();
    if (tid < 64)
        out[(size_t)b * 64 + tid] =
            b4[tid] + red[tid] + red[64 + tid] + red[128 + tid] + red[192 + tid];
}

extern "C" void kernel_launch(void* const* d_in, const int* in_sizes, int n_in,
                              void* d_out, int out_size, void* d_ws, size_t ws_size,
                              hipStream_t stream) {
    const float* queries     = (const float*)d_in[0];
    const float* keys        = (const float*)d_in[1];
    const int*   keys_length = (const int*)  d_in[2];
    const float* W1 = (const float*)d_in[3];
    const float* b1 = (const float*)d_in[4];
    const float* W2 = (const float*)d_in[5];
    const float* b2 = (const float*)d_in[6];
    const float* W3 = (const float*)d_in[7];
    const float* b3 = (const float*)d_in[8];
    const float* W4 = (const float*)d_in[9];
    const float* b4 = (const float*)d_in[10];
    float* out = (float*)d_out;

    const int Bn = in_sizes[2];   // 4096
    din_attn_kernel<<<Bn, 256, 0, stream>>>(
        queries, keys, keys_length, W1, b1, W2, b2, W3, b3, W4, b4, out);
}

// Round 2
// 323.699 us; speedup vs baseline: 1.1546x; 1.1546x over previous
//
#include <hip/hip_runtime.h>
#include <math.h>

// Problem constants: B=4096, T=200, D=64
#define TT 200
#define DD 64
#define MTS 72   // Mt row stride in bf16 elems (144 B rows: 16B-aligned, bank-spread)

typedef __attribute__((ext_vector_type(8))) short bf16x8;  // 8 bf16 = 4 VGPRs
typedef __attribute__((ext_vector_type(4))) float f32x4;

__device__ __forceinline__ float sigmoidf_(float x) {
    return 1.0f / (1.0f + __expf(-x));
}
// bf16 RNE convert via bit ops (no dependence on __hip_bfloat16 internals)
__device__ __forceinline__ short f2bf(float x) {
    unsigned u = __float_as_uint(x);
    u += 0x7fff + ((u >> 16) & 1);
    return (short)(u >> 16);
}
__device__ __forceinline__ float bf2f(short s) {
    return __uint_as_float(((unsigned)(unsigned short)s) << 16);
}
// split x into bf16 hi + bf16 lo (x ~= hi + lo, ~16-bit mantissa total)
__device__ __forceinline__ void build_frag(float4 v0, float4 v1, bf16x8& hi, bf16x8& lo) {
    float xs[8] = {v0.x, v0.y, v0.z, v0.w, v1.x, v1.y, v1.z, v1.w};
    #pragma unroll
    for (int j = 0; j < 8; j++) {
        short h = f2bf(xs[j]);
        hi[j] = h;
        lo[j] = f2bf(xs[j] - bf2f(h));
    }
}

__global__ __launch_bounds__(256) void din_attn_kernel(
    const float* __restrict__ queries,     // [B,64]
    const float* __restrict__ keys,        // [B,200,64]
    const int*   __restrict__ keys_length, // [B]
    const float* __restrict__ W1,          // [256,16]
    const float* __restrict__ b1,          // [16]
    const float* __restrict__ W2,          // [16,8]
    const float* __restrict__ b2,          // [8]
    const float* __restrict__ W3,          // [8,1]
    const float* __restrict__ b3,          // [1]
    const float* __restrict__ W4,          // [64,64]
    const float* __restrict__ b4,          // [64]
    float* __restrict__ out)               // [B,64]
{
    // Mt: folded first-layer weight, TRANSPOSED [h][d], split bf16 hi/lo
    __shared__ __align__(16) short MtHi[16 * MTS];   // 2304 B
    __shared__ __align__(16) short MtLo[16 * MTS];   // 2304 B
    __shared__ __align__(16) float H1s[208 * 16];    // 13312 B, sigmoided layer-1 out
    __shared__ float cpart[64 * 16];                 // fold scratch
    __shared__ float qs[64];
    __shared__ float cvec[16];
    __shared__ __align__(16) float w2s[16 * 8];
    __shared__ float w3s[8];
    __shared__ float b2s[8];
    __shared__ float b3sh[1];
    __shared__ float scoresS[256];
    __shared__ float red[4 * 64];
    __shared__ float tmpv[64];

    const int tid = threadIdx.x;
    const int b   = blockIdx.x;
    const int len = keys_length[b];
    const float* kb = keys + (size_t)b * (TT * DD);

    // ---- stage small operands ----
    if (tid < 64)        qs[tid]        = queries[b * DD + tid];
    else if (tid < 192)  w2s[tid - 64]  = W2[tid - 64];
    else if (tid < 200)  w3s[tid - 192] = W3[tid - 192];
    else if (tid < 208)  b2s[tid - 200] = b2[tid - 200];
    else if (tid == 208) b3sh[0]        = b3[0];
    __syncthreads();

    // ---- fold W1: M[d][h] = W1b - W1c + q[d]*W1d  (split bf16, transposed into Mt)
    //      cpart[d][h] = q[d]*(W1a + W1c)
    {
        const float4* W1v = (const float4*)W1;   // [256][4] of float4
        const int d  = tid >> 2;
        const int hg = tid & 3;
        const float q = qs[d];
        float4 a  = W1v[(0   + d) * 4 + hg];
        float4 bb = W1v[(64  + d) * 4 + hg];
        float4 cc = W1v[(128 + d) * 4 + hg];
        float4 dd = W1v[(192 + d) * 4 + hg];
        const int cbase = d * 16 + hg * 4;
        cpart[cbase + 0] = q * (a.x + cc.x);
        cpart[cbase + 1] = q * (a.y + cc.y);
        cpart[cbase + 2] = q * (a.z + cc.z);
        cpart[cbase + 3] = q * (a.w + cc.w);
        float mv[4];
        mv[0] = bb.x - cc.x + q * dd.x;
        mv[1] = bb.y - cc.y + q * dd.y;
        mv[2] = bb.z - cc.z + q * dd.z;
        mv[3] = bb.w - cc.w + q * dd.w;
        #pragma unroll
        for (int i = 0; i < 4; i++) {
            const int h = hg * 4 + i;
            short hi = f2bf(mv[i]);
            MtHi[h * MTS + d] = hi;
            MtLo[h * MTS + d] = f2bf(mv[i] - bf2f(hi));
        }
    }
    __syncthreads();
    if (tid < 16) {
        float s = b1[tid];
        for (int d = 0; d < DD; d++) s += cpart[d * 16 + tid];
        cvec[tid] = s;
    }
    __syncthreads();

    const int w    = tid >> 6;
    const int lane = tid & 63;
    const int m16  = lane & 15;
    const int quad = lane >> 4;

    // ---- layer-1 GEMM via MFMA: H1[t][h] = sigmoid( K[t,:] @ M[:,h] + c[h] )
    // A = K tile (m=t), B = M (k=d, n=h). Split-bf16: 3 mfma per k-half.
    {
        const int bb0 = m16 * MTS + quad * 8;     // B[k=quad*8+j][n=m16] from Mt[h][d]
        bf16x8 Bh0 = *(const bf16x8*)&MtHi[bb0];
        bf16x8 Bh1 = *(const bf16x8*)&MtHi[bb0 + 32];
        bf16x8 Bl0 = *(const bf16x8*)&MtLo[bb0];
        bf16x8 Bl1 = *(const bf16x8*)&MtLo[bb0 + 32];
        const float cv = cvec[m16];

        for (int tile = w; tile < 13; tile += 4) {
            int trow = tile * 16 + m16;
            if (trow > TT - 1) trow = TT - 1;      // clamp: rows 200..207 unused downstream
            const float* kp = kb + trow * 64 + quad * 8;
            float4 v0 = *(const float4*)(kp);          // k-half 0, j 0..3
            float4 v1 = *(const float4*)(kp + 4);      // k-half 0, j 4..7
            float4 v2 = *(const float4*)(kp + 32);     // k-half 1, j 0..3
            float4 v3 = *(const float4*)(kp + 36);     // k-half 1, j 4..7
            bf16x8 ah0, al0, ah1, al1;
            build_frag(v0, v1, ah0, al0);
            build_frag(v2, v3, ah1, al1);
            f32x4 acc = {0.f, 0.f, 0.f, 0.f};
            acc = __builtin_amdgcn_mfma_f32_16x16x32_bf16(ah0, Bh0, acc, 0, 0, 0);
            acc = __builtin_amdgcn_mfma_f32_16x16x32_bf16(ah0, Bl0, acc, 0, 0, 0);
            acc = __builtin_amdgcn_mfma_f32_16x16x32_bf16(al0, Bh0, acc, 0, 0, 0);
            acc = __builtin_amdgcn_mfma_f32_16x16x32_bf16(ah1, Bh1, acc, 0, 0, 0);
            acc = __builtin_amdgcn_mfma_f32_16x16x32_bf16(ah1, Bl1, acc, 0, 0, 0);
            acc = __builtin_amdgcn_mfma_f32_16x16x32_bf16(al1, Bh1, acc, 0, 0, 0);
            // C layout: col = lane&15 (=h), row = quad*4 + reg
            const int rb = tile * 16 + quad * 4;
            H1s[(rb + 0) * 16 + m16] = sigmoidf_(acc[0] + cv);
            H1s[(rb + 1) * 16 + m16] = sigmoidf_(acc[1] + cv);
            H1s[(rb + 2) * 16 + m16] = sigmoidf_(acc[2] + cv);
            H1s[(rb + 3) * 16 + m16] = sigmoidf_(acc[3] + cv);
        }
    }
    __syncthreads();

    // ---- layers 2..3 per-thread (t = tid), h2 stays in registers ----
    float sc = -INFINITY;
    if (tid < TT) {
        const float4* h1p = (const float4*)&H1s[tid * 16];
        float4 ha = h1p[0], hb = h1p[1], hc = h1p[2], hd = h1p[3];
        float hv[16] = {ha.x, ha.y, ha.z, ha.w, hb.x, hb.y, hb.z, hb.w,
                        hc.x, hc.y, hc.z, hc.w, hd.x, hd.y, hd.z, hd.w};
        float s2[8];
        #pragma unroll
        for (int k = 0; k < 8; k++) s2[k] = b2s[k];
        #pragma unroll
        for (int h = 0; h < 16; h++) {
            const float hh = hv[h];
            const float4* w2r = (const float4*)&w2s[h * 8];
            float4 wa = w2r[0], wb = w2r[1];
            s2[0] = fmaf(hh, wa.x, s2[0]);
            s2[1] = fmaf(hh, wa.y, s2[1]);
            s2[2] = fmaf(hh, wa.z, s2[2]);
            s2[3] = fmaf(hh, wa.w, s2[3]);
            s2[4] = fmaf(hh, wb.x, s2[4]);
            s2[5] = fmaf(hh, wb.y, s2[5]);
            s2[6] = fmaf(hh, wb.z, s2[6]);
            s2[7] = fmaf(hh, wb.w, s2[7]);
        }
        float s3 = b3sh[0];
        #pragma unroll
        for (int k = 0; k < 8; k++) s3 = fmaf(sigmoidf_(s2[k]), w3s[k], s3);
        if (tid >= len) s3 = -4294967295.0f;   // NEG_INF
        sc = s3 * 0.125f;                      // / sqrt(64)
    }

    // ---- softmax over T ----
    float m = sc;
    #pragma unroll
    for (int off = 32; off >= 1; off >>= 1) m = fmaxf(m, __shfl_xor(m, off, 64));
    if (lane == 0) red[w] = m;
    __syncthreads();
    m = fmaxf(fmaxf(red[0], red[1]), fmaxf(red[2], red[3]));

    float p = (tid < TT) ? __expf(sc - m) : 0.0f;
    float ssum = p;
    #pragma unroll
    for (int off = 32; off >= 1; off >>= 1) ssum += __shfl_xor(ssum, off, 64);
    __syncthreads();
    if (lane == 0) red[w] = ssum;
    __syncthreads();
    const float inv = 1.0f / (red[0] + red[1] + red[2] + red[3]);
    if (tid < TT) scoresS[tid] = p * inv;
    __syncthreads();

    // ---- weighted key sum: wave w covers 50 t's, lane = d; keys from global (L2-hot) ----
    float ws = 0.0f;
    #pragma unroll 5
    for (int t = w * 50; t < w * 50 + 50; t++)
        ws = fmaf(scoresS[t], kb[t * 64 + lane], ws);
    red[w * 64 + lane] = ws;
    __syncthreads();
    if (tid < 64) tmpv[tid] = red[tid] + red[64 + tid] + red[128 + tid] + red[192 + tid];
    __syncthreads();

    // ---- out = tmpv @ W4 + b4 ; wave w covers i in [16w,16w+16) ----
    float po = 0.0f;
    {
        const float* w4p = W4 + (size_t)(w * 16) * 64 + lane;
        #pragma unroll
        for (int i = 0; i < 16; i++)
            po = fmaf(tmpv[w * 16 + i], w4p[i * 64], po);
    }
    red[w * 64 + lane] = po;
    __syncthreads();
    if (tid < 64)
        out[(size_t)b * 64 + tid] =
            b4[tid] + red[tid] + red[64 + tid] + red[128 + tid] + red[192 + tid];
}

extern "C" void kernel_launch(void* const* d_in, const int* in_sizes, int n_in,
                              void* d_out, int out_size, void* d_ws, size_t ws_size,
                              hipStream_t stream) {
    const float* queries     = (const float*)d_in[0];
    const float* keys        = (const float*)d_in[1];
    const int*   keys_length = (const int*)  d_in[2];
    const float* W1 = (const float*)d_in[3];
    const float* b1 = (const float*)d_in[4];
    const float* W2 = (const float*)d_in[5];
    const float* b2 = (const float*)d_in[6];
    const float* W3 = (const float*)d_in[7];
    const float* b3 = (const float*)d_in[8];
    const float* W4 = (const float*)d_in[9];
    const float* b4 = (const float*)d_in[10];
    float* out = (float*)d_out;

    const int Bn = in_sizes[2];   // 4096
    din_attn_kernel<<<Bn, 256, 0, stream>>>(
        queries, keys, keys_length, W1, b1, W2, b2, W3, b3, W4, b4, out);
}

// Round 3
// 316.183 us; speedup vs baseline: 1.1821x; 1.0238x over previous
//
#include <hip/hip_runtime.h>
#include <math.h>

// Problem constants: B=4096, T=200, D=64
#define TT 200
#define DD 64
#define MTS 72   // Mt row stride in bf16 elems (144 B rows: 16B-aligned)

typedef __attribute__((ext_vector_type(8))) short bf16x8;  // 8 bf16 = 4 VGPRs
typedef __attribute__((ext_vector_type(4))) float f32x4;

__device__ __forceinline__ float sigmoidf_(float x) {
    return 1.0f / (1.0f + __expf(-x));
}
// bf16 RNE convert via bit ops
__device__ __forceinline__ short f2bf(float x) {
    unsigned u = __float_as_uint(x);
    u += 0x7fff + ((u >> 16) & 1);
    return (short)(u >> 16);
}
__device__ __forceinline__ float bf2f(short s) {
    return __uint_as_float(((unsigned)(unsigned short)s) << 16);
}
__device__ __forceinline__ void build_hi(float4 v0, float4 v1, bf16x8& hi) {
    float xs[8] = {v0.x, v0.y, v0.z, v0.w, v1.x, v1.y, v1.z, v1.w};
    #pragma unroll
    for (int j = 0; j < 8; j++) hi[j] = f2bf(xs[j]);
}

__global__ __launch_bounds__(256) void din_attn_kernel(
    const float* __restrict__ queries,     // [B,64]
    const float* __restrict__ keys,        // [B,200,64]
    const int*   __restrict__ keys_length, // [B]
    const float* __restrict__ W1,          // [256,16]
    const float* __restrict__ b1,          // [16]
    const float* __restrict__ W2,          // [16,8]
    const float* __restrict__ b2,          // [8]
    const float* __restrict__ W3,          // [8,1]
    const float* __restrict__ b3,          // [1]
    const float* __restrict__ W4,          // [64,64]
    const float* __restrict__ b4,          // [64]
    float* __restrict__ out)               // [B,64]
{
    __shared__ __align__(16) short MtHi[16 * MTS];   // 2304 B folded W1^T hi
    __shared__ __align__(16) short MtLo[16 * MTS];   // 2304 B folded W1^T lo
    __shared__ __align__(16) short H1s[208 * 16];    // 6656 B sigmoided layer-1 (bf16)
    __shared__ float cred[4 * 16];                   // cvec per-wave partials
    __shared__ __align__(16) float w2s[16 * 8];
    __shared__ float w3s[8];
    __shared__ float b2s[8];
    __shared__ float b3sh[1];
    __shared__ float scoresS[256];                   // unnormalized exp(sc - m)
    __shared__ float sred[8];                        // [0..3]=max, [4..7]=sum partials
    __shared__ float wred[4 * 64];
    __shared__ float tmpv[64];

    const int tid  = threadIdx.x;
    const int b    = blockIdx.x;
    const int w    = tid >> 6;
    const int lane = tid & 63;
    const int m16  = lane & 15;
    const int quad = lane >> 4;
    const int len  = keys_length[b];
    const float* kb = keys + (size_t)b * (TT * DD);

    // ---- prefetch this wave's FIRST scorer tile (independent of fold) ----
    int trow0 = w * 16 + m16;
    if (trow0 > TT - 1) trow0 = TT - 1;
    const float* kp0 = kb + trow0 * 64 + quad * 8;
    float4 c0 = *(const float4*)(kp0);
    float4 c1 = *(const float4*)(kp0 + 4);
    float4 c2 = *(const float4*)(kp0 + 32);
    float4 c3 = *(const float4*)(kp0 + 36);

    // ---- fold W1 (all 256 threads): d=tid>>2 handles 4 h's (hg=tid&3) ----
    {
        const int d  = tid >> 2;
        const int hg = tid & 3;
        const float q = queries[b * 64 + d];
        const float4* W1v = (const float4*)W1;   // [256][4] of float4
        float4 a  = W1v[(0   + d) * 4 + hg];
        float4 bb = W1v[(64  + d) * 4 + hg];
        float4 cc = W1v[(128 + d) * 4 + hg];
        float4 dd = W1v[(192 + d) * 4 + hg];
        float cp[4], mv[4];
        cp[0] = q * (a.x + cc.x);  mv[0] = bb.x - cc.x + q * dd.x;
        cp[1] = q * (a.y + cc.y);  mv[1] = bb.y - cc.y + q * dd.y;
        cp[2] = q * (a.z + cc.z);  mv[2] = bb.z - cc.z + q * dd.z;
        cp[3] = q * (a.w + cc.w);  mv[3] = bb.w - cc.w + q * dd.w;
        #pragma unroll
        for (int i = 0; i < 4; i++) {
            const int h = hg * 4 + i;
            short hi = f2bf(mv[i]);
            MtHi[h * MTS + d] = hi;
            MtLo[h * MTS + d] = f2bf(mv[i] - bf2f(hi));
        }
        // in-register reduce cp over the wave's 16 d values (lane bits 2..5 = d_local)
        #pragma unroll
        for (int mask = 4; mask <= 32; mask <<= 1) {
            #pragma unroll
            for (int i = 0; i < 4; i++) cp[i] += __shfl_xor(cp[i], mask, 64);
        }
        if (lane < 4) {
            #pragma unroll
            for (int i = 0; i < 4; i++) cred[w * 16 + lane * 4 + i] = cp[i];
        }
        // stage tiny operands (reads are after barrier #1)
        if (tid < 128)       w2s[tid]        = W2[tid];
        else if (tid < 136)  w3s[tid - 128]  = W3[tid - 128];
        else if (tid < 144)  b2s[tid - 136]  = b2[tid - 136];
        else if (tid == 144) b3sh[0]         = b3[0];
    }
    __syncthreads();   // #1: Mt, cred, w2s ready

    // ---- scorer: MFMA over 13 t-tiles, software-pipelined keys loads ----
    {
        const int bb0 = m16 * MTS + quad * 8;
        bf16x8 Bh0 = *(const bf16x8*)&MtHi[bb0];
        bf16x8 Bh1 = *(const bf16x8*)&MtHi[bb0 + 32];
        bf16x8 Bl0 = *(const bf16x8*)&MtLo[bb0];
        bf16x8 Bl1 = *(const bf16x8*)&MtLo[bb0 + 32];
        const float cv = b1[m16] + cred[0 + m16] + cred[16 + m16]
                       + cred[32 + m16] + cred[48 + m16];

        for (int tile = w; tile < 13; tile += 4) {
            // prefetch next tile
            float4 n0, n1, n2, n3;
            const int nt = tile + 4;
            if (nt < 13) {
                int trow = nt * 16 + m16;
                if (trow > TT - 1) trow = TT - 1;
                const float* kp = kb + trow * 64 + quad * 8;
                n0 = *(const float4*)(kp);
                n1 = *(const float4*)(kp + 4);
                n2 = *(const float4*)(kp + 32);
                n3 = *(const float4*)(kp + 36);
            }
            bf16x8 ah0, ah1;
            build_hi(c0, c1, ah0);
            build_hi(c2, c3, ah1);
            f32x4 acc = {0.f, 0.f, 0.f, 0.f};
            acc = __builtin_amdgcn_mfma_f32_16x16x32_bf16(ah0, Bh0, acc, 0, 0, 0);
            acc = __builtin_amdgcn_mfma_f32_16x16x32_bf16(ah0, Bl0, acc, 0, 0, 0);
            acc = __builtin_amdgcn_mfma_f32_16x16x32_bf16(ah1, Bh1, acc, 0, 0, 0);
            acc = __builtin_amdgcn_mfma_f32_16x16x32_bf16(ah1, Bl1, acc, 0, 0, 0);
            // C layout: col = m16 (=h), row = quad*4 + reg
            const int rb = tile * 16 + quad * 4;
            H1s[(rb + 0) * 16 + m16] = f2bf(sigmoidf_(acc[0] + cv));
            H1s[(rb + 1) * 16 + m16] = f2bf(sigmoidf_(acc[1] + cv));
            H1s[(rb + 2) * 16 + m16] = f2bf(sigmoidf_(acc[2] + cv));
            H1s[(rb + 3) * 16 + m16] = f2bf(sigmoidf_(acc[3] + cv));
            c0 = n0; c1 = n1; c2 = n2; c3 = n3;
        }
    }
    __syncthreads();   // #2: H1s ready

    // ---- prefetch epilogue operands (hidden behind layer2/softmax) ----
    float w4r[16];
    {
        const float* w4p = W4 + (size_t)(w * 16) * 64 + lane;
        #pragma unroll
        for (int i = 0; i < 16; i++) w4r[i] = w4p[i * 64];
    }
    float b4v = (tid < 64) ? b4[tid] : 0.0f;

    // ---- layers 2..3 per-thread (t = tid) ----
    float sc = -INFINITY;
    if (tid < TT) {
        bf16x8 h1a = *(const bf16x8*)&H1s[tid * 16];
        bf16x8 h1b = *(const bf16x8*)&H1s[tid * 16 + 8];
        float hv[16];
        #pragma unroll
        for (int j = 0; j < 8; j++) { hv[j] = bf2f(h1a[j]); hv[8 + j] = bf2f(h1b[j]); }
        float s2[8];
        #pragma unroll
        for (int k = 0; k < 8; k++) s2[k] = b2s[k];
        #pragma unroll
        for (int h = 0; h < 16; h++) {
            const float hh = hv[h];
            const float4* w2r = (const float4*)&w2s[h * 8];
            float4 wa = w2r[0], wb = w2r[1];
            s2[0] = fmaf(hh, wa.x, s2[0]);
            s2[1] = fmaf(hh, wa.y, s2[1]);
            s2[2] = fmaf(hh, wa.z, s2[2]);
            s2[3] = fmaf(hh, wa.w, s2[3]);
            s2[4] = fmaf(hh, wb.x, s2[4]);
            s2[5] = fmaf(hh, wb.y, s2[5]);
            s2[6] = fmaf(hh, wb.z, s2[6]);
            s2[7] = fmaf(hh, wb.w, s2[7]);
        }
        float s3 = b3sh[0];
        #pragma unroll
        for (int k = 0; k < 8; k++) s3 = fmaf(sigmoidf_(s2[k]), w3s[k], s3);
        if (tid >= len) s3 = -4294967295.0f;   // NEG_INF
        sc = s3 * 0.125f;                      // / sqrt(64)
    }

    // ---- softmax (unnormalized; normalize at tmpv) ----
    float m = sc;
    #pragma unroll
    for (int off = 32; off >= 1; off >>= 1) m = fmaxf(m, __shfl_xor(m, off, 64));
    if (lane == 0) sred[w] = m;
    __syncthreads();   // #3: max partials
    m = fmaxf(fmaxf(sred[0], sred[1]), fmaxf(sred[2], sred[3]));

    float p = (tid < TT) ? __expf(sc - m) : 0.0f;
    scoresS[tid] = p;
    float ssum = p;
    #pragma unroll
    for (int off = 32; off >= 1; off >>= 1) ssum += __shfl_xor(ssum, off, 64);
    if (lane == 0) sred[4 + w] = ssum;
    __syncthreads();   // #4: scoresS + sum partials

    // ---- weighted key sum: wave w covers 50 t's, lane = d (keys L2/L3-hot) ----
    float ws = 0.0f;
    #pragma unroll 10
    for (int t = w * 50; t < w * 50 + 50; t++)
        ws = fmaf(scoresS[t], kb[t * 64 + lane], ws);
    wred[w * 64 + lane] = ws;
    __syncthreads();   // #5
    if (tid < 64) {
        const float inv = 1.0f / (sred[4] + sred[5] + sred[6] + sred[7]);
        tmpv[tid] = (wred[tid] + wred[64 + tid] + wred[128 + tid] + wred[192 + tid]) * inv;
    }
    __syncthreads();   // #6

    // ---- out = tmpv @ W4 + b4 ; wave w covers i in [16w,16w+16) ----
    float po = 0.0f;
    #pragma unroll
    for (int i = 0; i < 16; i++) po = fmaf(tmpv[w * 16 + i], w4r[i], po);
    wred[w * 64 + lane] = po;
    __syncthreads();   // #7
    if (tid < 64)
        out[(size_t)b * 64 + tid] =
            b4v + wred[tid] + wred[64 + tid] + wred[128 + tid] + wred[192 + tid];
}

extern "C" void kernel_launch(void* const* d_in, const int* in_sizes, int n_in,
                              void* d_out, int out_size, void* d_ws, size_t ws_size,
                              hipStream_t stream) {
    const float* queries     = (const float*)d_in[0];
    const float* keys        = (const float*)d_in[1];
    const int*   keys_length = (const int*)  d_in[2];
    const float* W1 = (const float*)d_in[3];
    const float* b1 = (const float*)d_in[4];
    const float* W2 = (const float*)d_in[5];
    const float* b2 = (const float*)d_in[6];
    const float* W3 = (const float*)d_in[7];
    const float* b3 = (const float*)d_in[8];
    const float* W4 = (const float*)d_in[9];
    const float* b4 = (const float*)d_in[10];
    float* out = (float*)d_out;

    const int Bn = in_sizes[2];   // 4096
    din_attn_kernel<<<Bn, 256, 0, stream>>>(
        queries, keys, keys_length, W1, b1, W2, b2, W3, b3, W4, b4, out);
}